// Round 16
// baseline (223.682 us; speedup 1.0000x reference)
//
#include <hip/hip_runtime.h>
#include <hip/hip_bf16.h>

#define LL 4096
#define DM 96
#define DI 192
#define NS 16
#define RK 6
#define RKP 8              // padded stride for dt coeffs (16B alignment)
#define KD 4
#define CPROJ 38
#define NC (KD*DI*NS)      // 12288 independent chains
#define PT 32              // t-tile for k_proj
#define WS 196             // LDS row stride (4*odd -> quad-bank spread)
#define OT 16              // l-tile for k_out
#define IT 16              // l-tile for k_inproj
#define L2E 1.44269504f

__device__ __forceinline__ float bu(unsigned short u){
  return __uint_as_float(((unsigned int)u) << 16);
}
// raw param load: bf16 (f=1) or fp32 (f=0)
__device__ __forceinline__ float ldp(const void* p, size_t i, int f){
  return f ? bu(((const unsigned short*)p)[i]) : ((const float*)p)[i];
}

// inline dtype detect: 64 lanes sample even halfwords of x; bf16 data has sane exponents
__device__ __forceinline__ void detect_bf16(const unsigned short* __restrict__ xh, int tid, int* sflag){
  if (tid < 64){
    unsigned short u = xh[2*tid];
    int e = (u >> 7) & 0xFF;
    int sane = (e >= 107 && e <= 131) ? 1 : 0;
    unsigned long long m = __ballot(sane);
    if (tid == 0) *sflag = (__popcll(m) >= 32) ? 1 : 0;
  }
}

// -------- K1: in_proj GEMM; raw x and raw W; 16 l-rows per block --------
__global__ void __launch_bounds__(384) k_inproj(const void* __restrict__ xraw,
                         const void* __restrict__ wraw,
                         float* __restrict__ xx, float* __restrict__ z) {
  __shared__ float xr[IT*DM];      // 6 KB
  __shared__ int sflag;
  int tid = threadIdx.x; // 384
  detect_bf16((const unsigned short*)xraw, tid, &sflag);
  __syncthreads();
  int f = sflag;
  int l0 = blockIdx.x * IT;        // 256 blocks
  if (f){
    const unsigned short* xb = (const unsigned short*)xraw + (size_t)l0*DM;
    for (int i = tid; i < IT*DM; i += 384) xr[i] = bu(xb[i]);
  } else {
    const float* xf = (const float*)xraw + (size_t)l0*DM;
    for (int i = tid; i < IT*DM; i += 384) xr[i] = xf[i];
  }
  __syncthreads();
  int e = tid;
  float acc[IT];
  #pragma unroll
  for (int i=0;i<IT;i++) acc[i]=0.f;
  if (f){
    const unsigned short* wr = (const unsigned short*)wraw + (size_t)e*DM;
    for (int c=0;c<DM;c++){
      float wv = bu(wr[c]);
      #pragma unroll
      for (int i=0;i<IT;i++) acc[i] = fmaf(wv, xr[i*DM+c], acc[i]);
    }
  } else {
    const float* wr = (const float*)wraw + (size_t)e*DM;
    for (int c=0;c<DM;c++){
      float wv = wr[c];
      #pragma unroll
      for (int i=0;i<IT;i++) acc[i] = fmaf(wv, xr[i*DM+c], acc[i]);
    }
  }
  if (e < DI) {
    #pragma unroll
    for (int i=0;i<IT;i++) xx[(size_t)(l0+i)*DI + e] = acc[i];
  } else {
    int e2 = e - DI;
    #pragma unroll
    for (int i=0;i<IT;i++) z[(size_t)(l0+i)*DI + e2] = acc[i];
  }
}

// -------- K2: depthwise 3x3 conv + bias + SiLU; raw cw/cb; writes xc AND xct --------
__global__ void k_conv(const float* __restrict__ xx,
                       const void* __restrict__ cw,
                       const void* __restrict__ cb,
                       float* __restrict__ xc,
                       float* __restrict__ xct,
                       const unsigned short* __restrict__ xh) {
  __shared__ int sflag;
  int l = blockIdx.x;
  int d = threadIdx.x; // 192
  detect_bf16(xh, d, &sflag);
  __syncthreads();
  int f = sflag;
  int h = l >> 6, w = l & 63;
  float acc = ldp(cb, d, f);
  #pragma unroll
  for (int ki=0; ki<3; ki++){
    int hh = h + ki - 1;
    if ((unsigned)hh >= 64u) continue;
    #pragma unroll
    for (int kj=0;kj<3;kj++){
      int wj = w + kj - 1;
      if ((unsigned)wj >= 64u) continue;
      acc = fmaf(ldp(cw, d*9 + ki*3 + kj, f), xx[(hh*64+wj)*DI + d], acc);
    }
  }
  float v = acc / (1.f + __expf(-acc));
  xc[l*DI + d] = v;
  xct[(((w<<6)|h))*DI + d] = v;
}

__device__ __forceinline__ int dir_map(int k, int t){
  if (k==0) return t;
  if (k==1) return ((t&63)<<6) | (t>>6);
  if (k==2) return 4095 - t;
  int u = 4095 - t; return ((u&63)<<6) | (u>>6);
}

// -------- K3: x_dbl projection as register-tiled LDS GEMM; raw xpw --------
__global__ void __launch_bounds__(256) k_proj(const float* __restrict__ xc,
                       const void* __restrict__ xpw,
                       float* __restrict__ dts,
                       float* __restrict__ Bb, float* __restrict__ Cb,
                       const unsigned short* __restrict__ xh) {
  __shared__ float wl[CPROJ*WS];   // 29.8 KB
  __shared__ float xs[PT*WS];      // 25.1 KB
  __shared__ int sflag;
  int b = blockIdx.x;              // KD * 128
  int k = b >> 7;
  int t_base = (b & 127) * PT;
  int tid = threadIdx.x;
  detect_bf16(xh, tid, &sflag);
  __syncthreads();
  int f = sflag;
  for (int idx = tid; idx < CPROJ*DI; idx += 256){
    int cc = idx / DI, j = idx - cc*DI;
    wl[cc*WS + j] = ldp(xpw, (size_t)(k*CPROJ + cc)*DI + j, f);
  }
  for (int idx = tid; idx < PT*DI; idx += 256){
    int tt = idx / DI, j = idx - tt*DI;
    xs[tt*WS + j] = xc[dir_map(k, t_base + tt)*DI + j];
  }
  __syncthreads();
  int tg = tid & 7;        // t-group: cols {tg, tg+8, tg+16, tg+24}
  int ty = tid >> 3;       // 0..31: rows {ty, ty+32 if <38}
  int cc0 = ty;
  int has2 = (ty + 32 < CPROJ);
  int cc1 = has2 ? (ty + 32) : ty;
  float a0x=0.f,a0y=0.f,a0z=0.f,a0w=0.f;
  float a1x=0.f,a1y=0.f,a1z=0.f,a1w=0.f;
  const float4* w0p = (const float4*)&wl[cc0*WS];
  const float4* w1p = (const float4*)&wl[cc1*WS];
  const float4* x0p = (const float4*)&xs[(tg     )*WS];
  const float4* x1p = (const float4*)&xs[(tg +  8)*WS];
  const float4* x2p = (const float4*)&xs[(tg + 16)*WS];
  const float4* x3p = (const float4*)&xs[(tg + 24)*WS];
  #pragma unroll 4
  for (int jc = 0; jc < DI/4; jc++){
    float4 w0 = w0p[jc], w1 = w1p[jc];
    float4 x0 = x0p[jc], x1 = x1p[jc], x2 = x2p[jc], x3 = x3p[jc];
    a0x = fmaf(w0.x,x0.x,fmaf(w0.y,x0.y,fmaf(w0.z,x0.z,fmaf(w0.w,x0.w,a0x))));
    a0y = fmaf(w0.x,x1.x,fmaf(w0.y,x1.y,fmaf(w0.z,x1.z,fmaf(w0.w,x1.w,a0y))));
    a0z = fmaf(w0.x,x2.x,fmaf(w0.y,x2.y,fmaf(w0.z,x2.z,fmaf(w0.w,x2.w,a0z))));
    a0w = fmaf(w0.x,x3.x,fmaf(w0.y,x3.y,fmaf(w0.z,x3.z,fmaf(w0.w,x3.w,a0w))));
    a1x = fmaf(w1.x,x0.x,fmaf(w1.y,x0.y,fmaf(w1.z,x0.z,fmaf(w1.w,x0.w,a1x))));
    a1y = fmaf(w1.x,x1.x,fmaf(w1.y,x1.y,fmaf(w1.z,x1.z,fmaf(w1.w,x1.w,a1y))));
    a1z = fmaf(w1.x,x2.x,fmaf(w1.y,x2.y,fmaf(w1.z,x2.z,fmaf(w1.w,x2.w,a1z))));
    a1w = fmaf(w1.x,x3.x,fmaf(w1.y,x3.y,fmaf(w1.z,x3.z,fmaf(w1.w,x3.w,a1w))));
  }
  float accs0[4] = {a0x,a0y,a0z,a0w};
  float accs1[4] = {a1x,a1y,a1z,a1w};
  #pragma unroll
  for (int i=0;i<4;i++){
    int t = t_base + tg + 8*i;
    size_t kt = (size_t)k*LL + t;
    {
      int cc = cc0; float v = accs0[i];
      if (cc < RK)            dts[kt*RKP + cc] = v;
      else if (cc < RK+NS)    Bb [kt*NS + (cc-RK)] = v;
      else                    Cb [kt*NS + (cc-RK-NS)] = v;
    }
    if (has2){
      int cc = ty + 32; float v = accs1[i];
      if (cc < RK+NS)         Bb [kt*NS + (cc-RK)] = v;
      else                    Cb [kt*NS + (cc-RK-NS)] = v;
    }
  }
}

// -------- K4a: single scan pass; plain y stores; PH interleaved (P,H); raw params --------
template<int CHB>
__global__ void __launch_bounds__(256) k_scan1(
                      const float* __restrict__ xc_hw,
                      const float* __restrict__ xc_wh,
                      const float* __restrict__ dts,
                      const float* __restrict__ Bbuf,
                      const float* __restrict__ Cbuf,
                      const void* __restrict__ A_logs,
                      const void* __restrict__ dtw,
                      const void* __restrict__ dtb,
                      float* __restrict__ PH,
                      float* __restrict__ ydir,
                      const unsigned short* __restrict__ xh) {
  constexpr int CS = LL >> CHB;
  __shared__ int sflag;
  int b = blockIdx.x;             // ((k*3+dg3)<<CHB) | c
  int c = b & ((1<<CHB)-1);
  int kg = b >> CHB;
  int k = kg / 3, dg3 = kg - k*3;
  int tid = threadIdx.x;
  detect_bf16(xh, tid, &sflag);
  __syncthreads();
  int f = sflag;
  int dl = tid >> 2, nq = tid & 3;
  int d = dg3*64 + dl;
  int kd = k*DI + d;
  float A0 = -__expf(ldp(A_logs, (size_t)kd*NS + nq*4 + 0, f))*L2E;
  float A1 = -__expf(ldp(A_logs, (size_t)kd*NS + nq*4 + 1, f))*L2E;
  float A2 = -__expf(ldp(A_logs, (size_t)kd*NS + nq*4 + 2, f))*L2E;
  float A3 = -__expf(ldp(A_logs, (size_t)kd*NS + nq*4 + 3, f))*L2E;
  float bt = ldp(dtb, kd, f);
  float w0 = ldp(dtw, (size_t)kd*RK+0, f), w1 = ldp(dtw, (size_t)kd*RK+1, f);
  float w2 = ldp(dtw, (size_t)kd*RK+2, f), w3 = ldp(dtw, (size_t)kd*RK+3, f);
  float w4 = ldp(dtw, (size_t)kd*RK+4, f), w5 = ldp(dtw, (size_t)kd*RK+5, f);
  const float* dr = dts + ((size_t)k*LL + c*CS)*RKP;
  const float4* bp = (const float4*)(Bbuf + ((size_t)k*LL + c*CS)*NS) + nq;
  const float4* cp = (const float4*)(Cbuf + ((size_t)k*LL + c*CS)*NS) + nq;
  const float* xbase = (k & 1) ? xc_wh : xc_hw;
  int l0 = (k < 2) ? (c*CS) : (4095 - c*CS);
  int lstep = (k < 2) ? DI : -DI;
  const float* xp = xbase + (size_t)l0*DI + d;
  float* yp = ydir + ((size_t)k*LL + c*CS)*DI + d;
  float h0=0.f,h1=0.f,h2=0.f,h3=0.f, cumD=0.f;
  #pragma unroll
  for (int s=0; s<CS; s++){
    float4 lo = *(const float4*)(dr + s*RKP);
    float4 hi = *(const float4*)(dr + s*RKP + 4);
    float v = bt;
    v = fmaf(w0, lo.x, v); v = fmaf(w1, lo.y, v); v = fmaf(w2, lo.z, v);
    v = fmaf(w3, lo.w, v); v = fmaf(w4, hi.x, v); v = fmaf(w5, hi.y, v);
    float sp = (v > 20.f) ? v : __logf(1.f + __expf(v));
    cumD += sp;
    float sx = sp * xp[(ptrdiff_t)s*lstep];
    float4 bv = bp[s*4];
    float4 cv = cp[s*4];
    float a;
    a = exp2f(sp*A0); h0 = fmaf(a, h0, sx*bv.x);
    a = exp2f(sp*A1); h1 = fmaf(a, h1, sx*bv.y);
    a = exp2f(sp*A2); h2 = fmaf(a, h2, sx*bv.z);
    a = exp2f(sp*A3); h3 = fmaf(a, h3, sx*bv.w);
    float y = h0*cv.x + h1*cv.y + h2*cv.z + h3*cv.w;
    y += __shfl_xor(y, 1, 64);
    y += __shfl_xor(y, 2, 64);
    if (nq == 0) yp[s*DI] = y;     // plain store: unique writer per (k,t,d)
  }
  size_t base2 = ((size_t)c*NC + (size_t)kd*NS + nq*4)*2;
  *(float4*)&PH[base2]   = make_float4(exp2f(A0*cumD), h0, exp2f(A1*cumD), h1);
  *(float4*)&PH[base2+4] = make_float4(exp2f(A2*cumD), h2, exp2f(A3*cumD), h3);
}

// -------- K4b: phase-2 combine over interleaved PH; entry state written into .y --------
template<int CHB>
__global__ void __launch_bounds__(256) k_scan2(float2* __restrict__ PH) {
  constexpr int CH = 1 << CHB;
  int idx = blockIdx.x*256 + threadIdx.x;   // < 12288
  float h = 0.f;
  #pragma unroll 8
  for (int c=0;c<CH;c++){
    float2 ph = PH[(size_t)c*NC + idx];
    PH[(size_t)c*NC + idx].y = h;           // overwrite H with entry state
    h = fmaf(ph.x, h, ph.y);
  }
}

// -------- K4c: parallel correction; recomputes SD from dts (bit-identical to scan1) --------
template<int CHB>
__global__ void __launch_bounds__(192) k_corr(
                      const float* __restrict__ Cbuf,
                      const float* __restrict__ dts,
                      const void* __restrict__ A_logs,
                      const void* __restrict__ dtw,
                      const void* __restrict__ dtb,
                      const float2* __restrict__ PH,    // .y = entry states
                      float* __restrict__ ydir,
                      const unsigned short* __restrict__ xh) {
  constexpr int CS = LL >> CHB;
  __shared__ float cs[CS*NS];
  __shared__ int sflag;
  int b = blockIdx.x;              // KD << CHB
  int k = b >> CHB;
  int c = b & ((1<<CHB)-1);
  int d = threadIdx.x;             // 192
  detect_bf16(xh, d, &sflag);
  if (c == 0) return;              // entry state is zero -> no correction
  int t0 = c*CS;
  int kd = k*DI + d;
  for (int i = d; i < CS*NS; i += 192)
    cs[i] = Cbuf[((size_t)k*LL + t0)*NS + i];
  __syncthreads();
  int f = sflag;
  float bt = ldp(dtb, kd, f);
  float w0 = ldp(dtw, (size_t)kd*RK+0, f), w1 = ldp(dtw, (size_t)kd*RK+1, f);
  float w2 = ldp(dtw, (size_t)kd*RK+2, f), w3 = ldp(dtw, (size_t)kd*RK+3, f);
  float w4 = ldp(dtw, (size_t)kd*RK+4, f), w5 = ldp(dtw, (size_t)kd*RK+5, f);
  float A2[16], he[16];
  {
    const float2* hp = PH + (size_t)c*NC + (size_t)kd*NS;
    #pragma unroll
    for (int n=0;n<16;n++){
      A2[n] = -__expf(ldp(A_logs, (size_t)kd*NS + n, f))*L2E;
      he[n] = hp[n].y;
    }
  }
  const float* dr = dts + ((size_t)k*LL + t0)*RKP;
  float* yp = ydir + ((size_t)k*LL + t0)*DI + d;
  float cumD = 0.f;
  #pragma unroll 4
  for (int s=0; s<CS; s++){
    float4 lo = *(const float4*)(dr + s*RKP);
    float4 hi = *(const float4*)(dr + s*RKP + 4);
    float v = bt;
    v = fmaf(w0, lo.x, v); v = fmaf(w1, lo.y, v); v = fmaf(w2, lo.z, v);
    v = fmaf(w3, lo.w, v); v = fmaf(w4, hi.x, v); v = fmaf(w5, hi.y, v);
    float sp = (v > 20.f) ? v : __logf(1.f + __expf(v));
    cumD += sp;
    float corr = 0.f;
    #pragma unroll
    for (int n=0;n<16;n++)
      corr = fmaf(cs[s*NS+n]*exp2f(A2[n]*cumD), he[n], corr);
    yp[s*DI] += corr;        // unique owner: scan1 done, one block per chunk
  }
}

// -------- K5: fused gather + LayerNorm + gate + out_proj (raw params), 16-l tile --------
__global__ void __launch_bounds__(192) k_out(
                      const float* __restrict__ ydir,
                      const float* __restrict__ xc,
                      const float* __restrict__ z,
                      const void* __restrict__ Ds,
                      const void* __restrict__ ln_g,
                      const void* __restrict__ ln_b,
                      const void* __restrict__ opw,
                      void* __restrict__ out,
                      const unsigned short* __restrict__ xh) {
  __shared__ float gs[OT*WS];      // 12.5 KB: y -> g
  __shared__ float ps[2][OT][12];
  __shared__ float mv[2][OT];
  __shared__ int sflag;
  int tid = threadIdx.x;           // 192
  int d = tid;
  detect_bf16(xh, tid, &sflag);
  __syncthreads();
  int f = sflag;
  int l0 = blockIdx.x * OT;        // 256 blocks
  float dsum = ldp(Ds, d, f) + ldp(Ds, DI+d, f) + ldp(Ds, 2*DI+d, f) + ldp(Ds, 3*DI+d, f);
  // phase A: y for 16 rows at this d
  #pragma unroll 4
  for (int r=0;r<OT;r++){
    int l = l0 + r;
    int lt = ((l & 63) << 6) | (l >> 6);
    float y = ydir[(size_t)l*DI + d]
            + ydir[((size_t)LL   + lt)*DI + d]
            + ydir[((size_t)2*LL + (4095 - l))*DI + d]
            + ydir[((size_t)3*LL + (4095 - lt))*DI + d];
    gs[r*WS + d] = fmaf(xc[(size_t)l*DI + d], dsum, y);
  }
  __syncthreads();
  // phase B: per-row mean/var; 16 groups x 12 threads
  {
    int r = tid / 12, lane = tid - r*12;
    float s1 = 0.f, s2 = 0.f;
    for (int j = lane; j < DI; j += 12){
      float v = gs[r*WS + j];
      s1 += v; s2 += v*v;
    }
    ps[0][r][lane] = s1; ps[1][r][lane] = s2;
  }
  __syncthreads();
  if (tid < OT){
    float a = 0.f, bb = 0.f;
    #pragma unroll
    for (int j=0;j<12;j++){ a += ps[0][tid][j]; bb += ps[1][tid][j]; }
    float mu = a * (1.f/192.f);
    float var = bb * (1.f/192.f) - mu*mu;
    mv[0][tid] = mu; mv[1][tid] = rsqrtf(var + 1e-5f);
  }
  __syncthreads();
  // phase C: normalize + gate
  float lg = ldp(ln_g, d, f), lb = ldp(ln_b, d, f);
  #pragma unroll 4
  for (int r=0;r<OT;r++){
    float yn = (gs[r*WS + d] - mv[0][r]) * mv[1][r] * lg + lb;
    float zv = z[(size_t)(l0+r)*DI + d];
    gs[r*WS + d] = yn * (zv / (1.f + __expf(-zv)));
  }
  __syncthreads();
  // phase D: out_proj (unswitched on dtype)
  int half = tid / 96;             // rows half*8..half*8+7
  int e = tid - half*96;
  int r0 = half*8;
  float acc[8];
  #pragma unroll
  for (int i=0;i<8;i++) acc[i] = 0.f;
  if (f){
    const ushort4* wr4 = (const ushort4*)((const unsigned short*)opw + (size_t)e*DI);
    #pragma unroll 4
    for (int jc = 0; jc < DI/4; jc++){
      ushort4 u = wr4[jc];
      float wx = bu(u.x), wy = bu(u.y), wz = bu(u.z), ww = bu(u.w);
      #pragma unroll
      for (int i=0;i<8;i++){
        float4 gv = *(const float4*)&gs[(r0+i)*WS + jc*4];
        acc[i] = fmaf(wx,gv.x,fmaf(wy,gv.y,fmaf(wz,gv.z,fmaf(ww,gv.w,acc[i]))));
      }
    }
  } else {
    const float4* wrow = (const float4*)((const float*)opw + (size_t)e*DI);
    #pragma unroll 4
    for (int jc = 0; jc < DI/4; jc++){
      float4 w = wrow[jc];
      #pragma unroll
      for (int i=0;i<8;i++){
        float4 gv = *(const float4*)&gs[(r0+i)*WS + jc*4];
        acc[i] = fmaf(w.x,gv.x,fmaf(w.y,gv.y,fmaf(w.z,gv.z,fmaf(w.w,gv.w,acc[i]))));
      }
    }
  }
  #pragma unroll
  for (int i=0;i<8;i++){
    int l = l0 + r0 + i;
    if (f) ((__hip_bfloat16*)out)[l*DM + e] = __float2bfloat16(acc[i]);
    else   ((float*)out)[l*DM + e] = acc[i];
  }
}

extern "C" void kernel_launch(void* const* d_in, const int* in_sizes, int n_in,
                              void* d_out, int out_size, void* d_ws, size_t ws_size,
                              hipStream_t stream) {
  const unsigned short* xh = (const unsigned short*)d_in[0];
  float* ws = (float*)d_ws;
  float* xx     = ws;                        // 786432
  float* z      = xx + (size_t)LL*DI;        // 786432
  float* xc     = z  + (size_t)LL*DI;        // 786432
  float* xct    = xc + (size_t)LL*DI;        // 786432
  float* dts    = xct + (size_t)LL*DI;       // 131072 (RKP=8 padded)
  float* Bb     = dts + (size_t)KD*LL*RKP;   // 262144
  float* Cb     = Bb + (size_t)KD*LL*NS;     // 262144
  float* PH     = Cb + (size_t)KD*LL*NS;     // 2*CHn*NC
  // footprint(CHB=7): ~40.4 MB; (CHB=6): ~34 MB. ws_size measured 256 MiB.
  size_t need128 = (size_t)(4*786432 + 131072 + 2*262144
                            + 2*128*NC + (size_t)KD*LL*DI) * 4;
  int chBits = (ws_size >= need128) ? 7 : 6;
  int CHn = 1 << chBits;
  float* ydir = PH + 2*(size_t)CHn*NC;       // KD*LL*DI = 3145728

  k_inproj<<<LL/IT, 384, 0, stream>>>(d_in[0], d_in[1], xx, z);
  k_conv<<<LL, DI, 0, stream>>>(xx, d_in[2], d_in[3], xc, xct, xh);
  k_proj<<<KD*(LL/PT), 256, 0, stream>>>(xc, d_in[4], dts, Bb, Cb, xh);
  if (chBits == 7){
    k_scan1<7><<<KD*3*128, 256, 0, stream>>>(xc, xct, dts, Bb, Cb,
                                             d_in[7], d_in[5], d_in[6], PH, ydir, xh);
    k_scan2<7><<<NC/256, 256, 0, stream>>>((float2*)PH);
    k_corr<7><<<KD*128, 192, 0, stream>>>(Cb, dts, d_in[7], d_in[5], d_in[6],
                                          (const float2*)PH, ydir, xh);
  } else {
    k_scan1<6><<<KD*3*64, 256, 0, stream>>>(xc, xct, dts, Bb, Cb,
                                            d_in[7], d_in[5], d_in[6], PH, ydir, xh);
    k_scan2<6><<<NC/256, 256, 0, stream>>>((float2*)PH);
    k_corr<6><<<KD*64, 192, 0, stream>>>(Cb, dts, d_in[7], d_in[5], d_in[6],
                                         (const float2*)PH, ydir, xh);
  }
  k_out<<<LL/OT, 192, 0, stream>>>(ydir, xc, z, d_in[8], d_in[9], d_in[10], d_in[11],
                                   d_out, xh);
}

// Round 17
// 201.869 us; speedup vs baseline: 1.1081x; 1.1081x over previous
//
#include <hip/hip_runtime.h>
#include <hip/hip_bf16.h>

#define LL 4096
#define DM 96
#define DI 192
#define NS 16
#define RK 6
#define RKP 8              // padded stride for dt coeffs (16B alignment)
#define KD 4
#define CPROJ 38
#define NC (KD*DI*NS)      // 12288 independent chains
#define PT 32              // t-tile for k_proj
#define WS 196             // LDS row stride (4*odd -> quad-bank spread)
#define OT 16              // l-tile for k_out
#define L2E 1.44269504f

__device__ __forceinline__ float b2f(__hip_bfloat16 v){ return __bfloat162float(v); }

// inline dtype detect: 64 lanes sample even halfwords of x; bf16 data has sane exponents
__device__ __forceinline__ void detect_bf16(const unsigned short* __restrict__ xh, int tid, int* sflag){
  if (tid < 64){
    unsigned short u = xh[2*tid];
    int e = (u >> 7) & 0xFF;
    int sane = (e >= 107 && e <= 131) ? 1 : 0;
    unsigned long long m = __ballot(sane);
    if (tid == 0) *sflag = (__popcll(m) >= 32) ? 1 : 0;
  }
}

// -------- K0: convert params (inputs 1..11) to fp32 (self-detecting); x handled raw --------
struct P12 { const void* p[12]; };
__global__ void k_convert_all(P12 ptrs, float* __restrict__ dst) {
  const int off[12] = {0,36864,38592,38784,67968,72576,73344,85632,86400,86592,86784,105216};
  __shared__ int sflag;
  detect_bf16((const unsigned short*)ptrs.p[0], threadIdx.x, &sflag);
  __syncthreads();
  int f = sflag;
  int i = blockIdx.x * 256 + threadIdx.x;
  if (i >= 105216) return;
  int j = 0;
  #pragma unroll
  for (int s = 1; s < 11; s++) if (i >= off[s]) j = s;
  int e = i - off[j];
  const void* src = ptrs.p[j+1];
  if (f) dst[i] = b2f(((const __hip_bfloat16*)src)[e]);
  else   dst[i] = ((const float*)src)[e];
}

// -------- K1: in_proj GEMM; reads raw x (dtype-branch), converted w --------
__global__ void k_inproj(const void* __restrict__ xraw,
                         const float* __restrict__ w,
                         float* __restrict__ xx, float* __restrict__ z) {
  __shared__ float xr[8*DM];
  __shared__ int sflag;
  int tid = threadIdx.x; // 384
  detect_bf16((const unsigned short*)xraw, tid, &sflag);
  __syncthreads();
  int l0 = blockIdx.x * 8;
  if (sflag){
    const __hip_bfloat16* xb = (const __hip_bfloat16*)xraw + (size_t)l0*DM;
    for (int i = tid; i < 8*DM; i += 384) xr[i] = b2f(xb[i]);
  } else {
    const float* xf = (const float*)xraw + (size_t)l0*DM;
    for (int i = tid; i < 8*DM; i += 384) xr[i] = xf[i];
  }
  __syncthreads();
  int e = tid;
  float acc[8];
  #pragma unroll
  for (int i=0;i<8;i++) acc[i]=0.f;
  const float* wr = w + e*DM;
  for (int c=0;c<DM;c++){
    float wv = wr[c];
    #pragma unroll
    for (int i=0;i<8;i++) acc[i] = fmaf(wv, xr[i*DM+c], acc[i]);
  }
  if (e < DI) {
    #pragma unroll
    for (int i=0;i<8;i++) xx[(l0+i)*DI + e] = acc[i];
  } else {
    int e2 = e - DI;
    #pragma unroll
    for (int i=0;i<8;i++) z[(l0+i)*DI + e2] = acc[i];
  }
}

// -------- K2: depthwise 3x3 conv + bias + SiLU; writes xc AND transposed xct --------
__global__ void k_conv(const float* __restrict__ xx,
                       const float* __restrict__ cw,
                       const float* __restrict__ cb,
                       float* __restrict__ xc,
                       float* __restrict__ xct) {
  int l = blockIdx.x;
  int d = threadIdx.x; // 192
  int h = l >> 6, w = l & 63;
  float acc = cb[d];
  #pragma unroll
  for (int ki=0; ki<3; ki++){
    int hh = h + ki - 1;
    if ((unsigned)hh >= 64u) continue;
    #pragma unroll
    for (int kj=0;kj<3;kj++){
      int wj = w + kj - 1;
      if ((unsigned)wj >= 64u) continue;
      acc = fmaf(cw[d*9 + ki*3 + kj], xx[(hh*64+wj)*DI + d], acc);
    }
  }
  float v = acc / (1.f + __expf(-acc));
  xc[l*DI + d] = v;
  xct[(((w<<6)|h))*DI + d] = v;
}

__device__ __forceinline__ int dir_map(int k, int t){
  if (k==0) return t;
  if (k==1) return ((t&63)<<6) | (t>>6);
  if (k==2) return 4095 - t;
  int u = 4095 - t; return ((u&63)<<6) | (u>>6);
}

// -------- K3: x_dbl projection as register-tiled LDS GEMM --------
__global__ void __launch_bounds__(256) k_proj(const float* __restrict__ xc,
                       const float* __restrict__ xpw,
                       float* __restrict__ dts,
                       float* __restrict__ Bb, float* __restrict__ Cb) {
  __shared__ float wl[CPROJ*WS];   // 29.8 KB
  __shared__ float xs[PT*WS];      // 25.1 KB
  int b = blockIdx.x;              // KD * 128
  int k = b >> 7;
  int t_base = (b & 127) * PT;
  int tid = threadIdx.x;
  for (int idx = tid; idx < CPROJ*DI; idx += 256){
    int cc = idx / DI, j = idx - cc*DI;
    wl[cc*WS + j] = xpw[(k*CPROJ + cc)*DI + j];
  }
  for (int idx = tid; idx < PT*DI; idx += 256){
    int tt = idx / DI, j = idx - tt*DI;
    xs[tt*WS + j] = xc[dir_map(k, t_base + tt)*DI + j];
  }
  __syncthreads();
  int tg = tid & 7;        // t-group: cols {tg, tg+8, tg+16, tg+24}
  int ty = tid >> 3;       // 0..31: rows {ty, ty+32 if <38}
  int cc0 = ty;
  int has2 = (ty + 32 < CPROJ);
  int cc1 = has2 ? (ty + 32) : ty;
  float a0x=0.f,a0y=0.f,a0z=0.f,a0w=0.f;
  float a1x=0.f,a1y=0.f,a1z=0.f,a1w=0.f;
  const float4* w0p = (const float4*)&wl[cc0*WS];
  const float4* w1p = (const float4*)&wl[cc1*WS];
  const float4* x0p = (const float4*)&xs[(tg     )*WS];
  const float4* x1p = (const float4*)&xs[(tg +  8)*WS];
  const float4* x2p = (const float4*)&xs[(tg + 16)*WS];
  const float4* x3p = (const float4*)&xs[(tg + 24)*WS];
  #pragma unroll 4
  for (int jc = 0; jc < DI/4; jc++){
    float4 w0 = w0p[jc], w1 = w1p[jc];
    float4 x0 = x0p[jc], x1 = x1p[jc], x2 = x2p[jc], x3 = x3p[jc];
    a0x = fmaf(w0.x,x0.x,fmaf(w0.y,x0.y,fmaf(w0.z,x0.z,fmaf(w0.w,x0.w,a0x))));
    a0y = fmaf(w0.x,x1.x,fmaf(w0.y,x1.y,fmaf(w0.z,x1.z,fmaf(w0.w,x1.w,a0y))));
    a0z = fmaf(w0.x,x2.x,fmaf(w0.y,x2.y,fmaf(w0.z,x2.z,fmaf(w0.w,x2.w,a0z))));
    a0w = fmaf(w0.x,x3.x,fmaf(w0.y,x3.y,fmaf(w0.z,x3.z,fmaf(w0.w,x3.w,a0w))));
    a1x = fmaf(w1.x,x0.x,fmaf(w1.y,x0.y,fmaf(w1.z,x0.z,fmaf(w1.w,x0.w,a1x))));
    a1y = fmaf(w1.x,x1.x,fmaf(w1.y,x1.y,fmaf(w1.z,x1.z,fmaf(w1.w,x1.w,a1y))));
    a1z = fmaf(w1.x,x2.x,fmaf(w1.y,x2.y,fmaf(w1.z,x2.z,fmaf(w1.w,x2.w,a1z))));
    a1w = fmaf(w1.x,x3.x,fmaf(w1.y,x3.y,fmaf(w1.z,x3.z,fmaf(w1.w,x3.w,a1w))));
  }
  float accs0[4] = {a0x,a0y,a0z,a0w};
  float accs1[4] = {a1x,a1y,a1z,a1w};
  #pragma unroll
  for (int i=0;i<4;i++){
    int t = t_base + tg + 8*i;
    size_t kt = (size_t)k*LL + t;
    {
      int cc = cc0; float v = accs0[i];
      if (cc < RK)            dts[kt*RKP + cc] = v;
      else if (cc < RK+NS)    Bb [kt*NS + (cc-RK)] = v;
      else                    Cb [kt*NS + (cc-RK-NS)] = v;
    }
    if (has2){
      int cc = ty + 32; float v = accs1[i];
      if (cc < RK+NS)         Bb [kt*NS + (cc-RK)] = v;
      else                    Cb [kt*NS + (cc-RK-NS)] = v;
    }
  }
}

// -------- K4a: single scan pass; plain y stores; PH interleaved (P,H) --------
template<int CHB>
__global__ void __launch_bounds__(256) k_scan1(
                      const float* __restrict__ xc_hw,
                      const float* __restrict__ xc_wh,
                      const float* __restrict__ dts,
                      const float* __restrict__ Bbuf,
                      const float* __restrict__ Cbuf,
                      const float* __restrict__ A_logs,
                      const float* __restrict__ dtw,
                      const float* __restrict__ dtb,
                      float* __restrict__ PH,
                      float* __restrict__ ydir) {
  constexpr int CS = LL >> CHB;
  int b = blockIdx.x;             // ((k*3+dg3)<<CHB) | c
  int c = b & ((1<<CHB)-1);
  int kg = b >> CHB;
  int k = kg / 3, dg3 = kg - k*3;
  int tid = threadIdx.x;
  int dl = tid >> 2, nq = tid & 3;
  int d = dg3*64 + dl;
  int kd = k*DI + d;
  float4 Al = *(const float4*)&A_logs[kd*NS + nq*4];
  float A0 = -__expf(Al.x)*L2E, A1 = -__expf(Al.y)*L2E;
  float A2 = -__expf(Al.z)*L2E, A3 = -__expf(Al.w)*L2E;
  float bt = dtb[kd];
  float w0 = dtw[kd*RK+0], w1 = dtw[kd*RK+1], w2 = dtw[kd*RK+2];
  float w3 = dtw[kd*RK+3], w4 = dtw[kd*RK+4], w5 = dtw[kd*RK+5];
  const float* dr = dts + ((size_t)k*LL + c*CS)*RKP;
  const float4* bp = (const float4*)(Bbuf + ((size_t)k*LL + c*CS)*NS) + nq;
  const float4* cp = (const float4*)(Cbuf + ((size_t)k*LL + c*CS)*NS) + nq;
  const float* xbase = (k & 1) ? xc_wh : xc_hw;
  int l0 = (k < 2) ? (c*CS) : (4095 - c*CS);
  int lstep = (k < 2) ? DI : -DI;
  const float* xp = xbase + (size_t)l0*DI + d;
  float* yp = ydir + ((size_t)k*LL + c*CS)*DI + d;
  float h0=0.f,h1=0.f,h2=0.f,h3=0.f, cumD=0.f;
  #pragma unroll
  for (int s=0; s<CS; s++){
    float4 lo = *(const float4*)(dr + s*RKP);
    float4 hi = *(const float4*)(dr + s*RKP + 4);
    float v = bt;
    v = fmaf(w0, lo.x, v); v = fmaf(w1, lo.y, v); v = fmaf(w2, lo.z, v);
    v = fmaf(w3, lo.w, v); v = fmaf(w4, hi.x, v); v = fmaf(w5, hi.y, v);
    float sp = (v > 20.f) ? v : __logf(1.f + __expf(v));
    cumD += sp;
    float sx = sp * xp[(ptrdiff_t)s*lstep];
    float4 bv = bp[s*4];
    float4 cv = cp[s*4];
    float a;
    a = exp2f(sp*A0); h0 = fmaf(a, h0, sx*bv.x);
    a = exp2f(sp*A1); h1 = fmaf(a, h1, sx*bv.y);
    a = exp2f(sp*A2); h2 = fmaf(a, h2, sx*bv.z);
    a = exp2f(sp*A3); h3 = fmaf(a, h3, sx*bv.w);
    float y = h0*cv.x + h1*cv.y + h2*cv.z + h3*cv.w;
    y += __shfl_xor(y, 1, 64);
    y += __shfl_xor(y, 2, 64);
    if (nq == 0) yp[s*DI] = y;     // plain store: unique writer per (k,t,d)
  }
  size_t base2 = ((size_t)c*NC + (size_t)kd*NS + nq*4)*2;
  *(float4*)&PH[base2]   = make_float4(exp2f(A0*cumD), h0, exp2f(A1*cumD), h1);
  *(float4*)&PH[base2+4] = make_float4(exp2f(A2*cumD), h2, exp2f(A3*cumD), h3);
}

// -------- K4b: phase-2 combine over interleaved PH; entry state written into .y --------
template<int CHB>
__global__ void __launch_bounds__(256) k_scan2(float2* __restrict__ PH) {
  constexpr int CH = 1 << CHB;
  int idx = blockIdx.x*256 + threadIdx.x;   // < 12288
  float h = 0.f;
  #pragma unroll 8
  for (int c=0;c<CH;c++){
    float2 ph = PH[(size_t)c*NC + idx];
    PH[(size_t)c*NC + idx].y = h;           // overwrite H with entry state
    h = fmaf(ph.x, h, ph.y);
  }
}

// -------- K4c: parallel correction; recomputes SD from dts (bit-identical to scan1) --------
template<int CHB>
__global__ void __launch_bounds__(192) k_corr(
                      const float* __restrict__ Cbuf,
                      const float* __restrict__ dts,
                      const float* __restrict__ A_logs,
                      const float* __restrict__ dtw,
                      const float* __restrict__ dtb,
                      const float2* __restrict__ PH,    // .y = entry states
                      float* __restrict__ ydir) {
  constexpr int CS = LL >> CHB;
  int b = blockIdx.x;              // KD << CHB
  int k = b >> CHB;
  int c = b & ((1<<CHB)-1);
  if (c == 0) return;              // entry state is zero -> no correction
  int t0 = c*CS;
  int d = threadIdx.x;             // 192
  int kd = k*DI + d;
  __shared__ float cs[CS*NS];
  for (int i = d; i < CS*NS; i += 192)
    cs[i] = Cbuf[((size_t)k*LL + t0)*NS + i];
  float bt = dtb[kd];
  float w0 = dtw[kd*RK+0], w1 = dtw[kd*RK+1], w2 = dtw[kd*RK+2];
  float w3 = dtw[kd*RK+3], w4 = dtw[kd*RK+4], w5 = dtw[kd*RK+5];
  float A2[16], he[16];
  {
    const float4* ap = (const float4*)&A_logs[kd*NS];
    const float2* hp = PH + (size_t)c*NC + (size_t)kd*NS;
    #pragma unroll
    for (int i=0;i<4;i++){
      float4 av = ap[i];
      A2[4*i+0] = -__expf(av.x)*L2E; A2[4*i+1] = -__expf(av.y)*L2E;
      A2[4*i+2] = -__expf(av.z)*L2E; A2[4*i+3] = -__expf(av.w)*L2E;
    }
    #pragma unroll
    for (int n=0;n<16;n++) he[n] = hp[n].y;
  }
  __syncthreads();
  const float* dr = dts + ((size_t)k*LL + t0)*RKP;
  float* yp = ydir + ((size_t)k*LL + t0)*DI + d;
  float cumD = 0.f;
  #pragma unroll 4
  for (int s=0; s<CS; s++){
    float4 lo = *(const float4*)(dr + s*RKP);
    float4 hi = *(const float4*)(dr + s*RKP + 4);
    float v = bt;
    v = fmaf(w0, lo.x, v); v = fmaf(w1, lo.y, v); v = fmaf(w2, lo.z, v);
    v = fmaf(w3, lo.w, v); v = fmaf(w4, hi.x, v); v = fmaf(w5, hi.y, v);
    float sp = (v > 20.f) ? v : __logf(1.f + __expf(v));
    cumD += sp;                    // same fma order as scan1 -> bit-identical
    float corr = 0.f;
    #pragma unroll
    for (int n=0;n<16;n++)
      corr = fmaf(cs[s*NS+n]*exp2f(A2[n]*cumD), he[n], corr);
    yp[s*DI] += corr;        // unique owner: scan1 done, one block per chunk
  }
}

// -------- K5: fused gather + LayerNorm + gate + out_proj, 16-l tile --------
__global__ void __launch_bounds__(192) k_out(
                      const float* __restrict__ ydir,
                      const float* __restrict__ xc,
                      const float* __restrict__ z,
                      const float* __restrict__ Ds,
                      const float* __restrict__ ln_g,
                      const float* __restrict__ ln_b,
                      const float* __restrict__ opw,
                      void* __restrict__ out,
                      const unsigned short* __restrict__ xh) {
  __shared__ float gs[OT*WS];      // 12.5 KB: y -> g
  __shared__ float ps[2][OT][12];
  __shared__ float mv[2][OT];
  __shared__ int sflag;
  int tid = threadIdx.x;           // 192
  int d = tid;
  detect_bf16(xh, tid, &sflag);
  int l0 = blockIdx.x * OT;        // 256 blocks
  float dsum = Ds[d] + Ds[DI+d] + Ds[2*DI+d] + Ds[3*DI+d];
  // phase A: y for 16 rows at this d
  #pragma unroll 4
  for (int r=0;r<OT;r++){
    int l = l0 + r;
    int lt = ((l & 63) << 6) | (l >> 6);
    float y = ydir[(size_t)l*DI + d]
            + ydir[((size_t)LL   + lt)*DI + d]
            + ydir[((size_t)2*LL + (4095 - l))*DI + d]
            + ydir[((size_t)3*LL + (4095 - lt))*DI + d];
    gs[r*WS + d] = fmaf(xc[(size_t)l*DI + d], dsum, y);
  }
  __syncthreads();
  // phase B: per-row mean/var; 16 groups x 12 threads
  {
    int r = tid / 12, lane = tid - r*12;
    float s1 = 0.f, s2 = 0.f;
    for (int j = lane; j < DI; j += 12){
      float v = gs[r*WS + j];
      s1 += v; s2 += v*v;
    }
    ps[0][r][lane] = s1; ps[1][r][lane] = s2;
  }
  __syncthreads();
  if (tid < OT){
    float a = 0.f, bb = 0.f;
    #pragma unroll
    for (int j=0;j<12;j++){ a += ps[0][tid][j]; bb += ps[1][tid][j]; }
    float mu = a * (1.f/192.f);
    float var = bb * (1.f/192.f) - mu*mu;
    mv[0][tid] = mu; mv[1][tid] = rsqrtf(var + 1e-5f);
  }
  __syncthreads();
  // phase C: normalize + gate
  float lg = ln_g[d], lb = ln_b[d];
  #pragma unroll 4
  for (int r=0;r<OT;r++){
    float yn = (gs[r*WS + d] - mv[0][r]) * mv[1][r] * lg + lb;
    float zv = z[(size_t)(l0+r)*DI + d];
    gs[r*WS + d] = yn * (zv / (1.f + __expf(-zv)));
  }
  __syncthreads();
  // phase D: out_proj
  int half = tid / 96;             // rows half*8..half*8+7
  int e = tid - half*96;
  int r0 = half*8;
  float acc[8];
  #pragma unroll
  for (int i=0;i<8;i++) acc[i] = 0.f;
  const float4* wrow = (const float4*)(opw + e*DI);
  #pragma unroll 4
  for (int jc = 0; jc < DI/4; jc++){
    float4 w = wrow[jc];
    #pragma unroll
    for (int i=0;i<8;i++){
      float4 gv = *(const float4*)&gs[(r0+i)*WS + jc*4];
      acc[i] = fmaf(w.x,gv.x,fmaf(w.y,gv.y,fmaf(w.z,gv.z,fmaf(w.w,gv.w,acc[i]))));
    }
  }
  int f = sflag;
  #pragma unroll
  for (int i=0;i<8;i++){
    int l = l0 + r0 + i;
    if (f) ((__hip_bfloat16*)out)[l*DM + e] = __float2bfloat16(acc[i]);
    else   ((float*)out)[l*DM + e] = acc[i];
  }
}

extern "C" void kernel_launch(void* const* d_in, const int* in_sizes, int n_in,
                              void* d_out, int out_size, void* d_ws, size_t ws_size,
                              hipStream_t stream) {
  float* ws = (float*)d_ws;
  float* cvt = ws + 16;
  const int off[12] = {0,36864,38592,38784,67968,72576,73344,85632,86400,86592,86784,105216};
  float* c[12];
  c[0] = nullptr;                            // x stays raw
  for (int i = 1; i < 12; i++) c[i] = cvt + off[i-1];

  float* big    = cvt + 105216;
  float* xx     = big;                       // 786432
  float* z      = xx + (size_t)LL*DI;        // 786432
  float* xc     = z  + (size_t)LL*DI;        // 786432
  float* xct    = xc + (size_t)LL*DI;        // 786432
  float* dts    = xct + (size_t)LL*DI;       // 131072 (RKP=8 padded)
  float* Bb     = dts + (size_t)KD*LL*RKP;   // 262144
  float* Cb     = Bb + (size_t)KD*LL*NS;     // 262144
  float* PH     = Cb + (size_t)KD*LL*NS;     // 2*CHn*NC
  // footprint(CHB=7): ~39 MB; (CHB=6): ~33 MB. ws_size measured 256 MiB.
  size_t need128 = (size_t)(16 + 105216 + 4*786432 + 131072 + 2*262144
                            + 2*128*NC + (size_t)KD*LL*DI) * 4;
  int chBits = (ws_size >= need128) ? 7 : 6;
  int CHn = 1 << chBits;
  float* ydir = PH + 2*(size_t)CHn*NC;       // KD*LL*DI = 3145728

  P12 ptrs;
  for (int i = 0; i < 12; i++) ptrs.p[i] = d_in[i];
  k_convert_all<<<(105216 + 255)/256, 256, 0, stream>>>(ptrs, cvt);

  k_inproj<<<LL/8, 384, 0, stream>>>(d_in[0], c[1], xx, z);
  k_conv<<<LL, DI, 0, stream>>>(xx, c[2], c[3], xc, xct);
  k_proj<<<KD*(LL/PT), 256, 0, stream>>>(xc, c[4], dts, Bb, Cb);
  if (chBits == 7){
    k_scan1<7><<<KD*3*128, 256, 0, stream>>>(xc, xct, dts, Bb, Cb, c[7], c[5], c[6],
                                             PH, ydir);
    k_scan2<7><<<NC/256, 256, 0, stream>>>((float2*)PH);
    k_corr<7><<<KD*128, 192, 0, stream>>>(Cb, dts, c[7], c[5], c[6],
                                          (const float2*)PH, ydir);
  } else {
    k_scan1<6><<<KD*3*64, 256, 0, stream>>>(xc, xct, dts, Bb, Cb, c[7], c[5], c[6],
                                            PH, ydir);
    k_scan2<6><<<NC/256, 256, 0, stream>>>((float2*)PH);
    k_corr<6><<<KD*64, 192, 0, stream>>>(Cb, dts, c[7], c[5], c[6],
                                         (const float2*)PH, ydir);
  }
  k_out<<<LL/OT, 192, 0, stream>>>(ydir, xc, z, c[8], c[9], c[10], c[11], d_out,
                                   (const unsigned short*)d_in[0]);
}

// Round 18
// 199.746 us; speedup vs baseline: 1.1198x; 1.0106x over previous
//
#include <hip/hip_runtime.h>
#include <hip/hip_bf16.h>

#define LL 4096
#define DM 96
#define DI 192
#define NS 16
#define RK 6
#define RKP 8              // padded stride for dt coeffs (16B alignment)
#define KD 4
#define CPROJ 38
#define NC (KD*DI*NS)      // 12288 independent chains
#define PT 32              // t-tile for k_proj
#define WS 196             // LDS row stride (4*odd -> quad-bank spread)
#define OT 16              // l-tile for k_out
#define L2E 1.44269504f

__device__ __forceinline__ float b2f(__hip_bfloat16 v){ return __bfloat162float(v); }

// inline dtype detect: 64 lanes sample even halfwords of x; bf16 data has sane exponents
__device__ __forceinline__ void detect_bf16(const unsigned short* __restrict__ xh, int tid, int* sflag){
  if (tid < 64){
    unsigned short u = xh[2*tid];
    int e = (u >> 7) & 0xFF;
    int sane = (e >= 107 && e <= 131) ? 1 : 0;
    unsigned long long m = __ballot(sane);
    if (tid == 0) *sflag = (__popcll(m) >= 32) ? 1 : 0;
  }
}

// -------- K0: convert params (inputs 1..11) to fp32 (self-detecting); x handled raw --------
struct P12 { const void* p[12]; };
__global__ void k_convert_all(P12 ptrs, float* __restrict__ dst) {
  const int off[12] = {0,36864,38592,38784,67968,72576,73344,85632,86400,86592,86784,105216};
  __shared__ int sflag;
  detect_bf16((const unsigned short*)ptrs.p[0], threadIdx.x, &sflag);
  __syncthreads();
  int f = sflag;
  int i = blockIdx.x * 256 + threadIdx.x;
  if (i >= 105216) return;
  int j = 0;
  #pragma unroll
  for (int s = 1; s < 11; s++) if (i >= off[s]) j = s;
  int e = i - off[j];
  const void* src = ptrs.p[j+1];
  if (f) dst[i] = b2f(((const __hip_bfloat16*)src)[e]);
  else   dst[i] = ((const float*)src)[e];
}

// -------- K1: in_proj GEMM; raw x (dtype-branch), converted W via float4 --------
__global__ void k_inproj(const void* __restrict__ xraw,
                         const float* __restrict__ w,
                         float* __restrict__ xx, float* __restrict__ z) {
  __shared__ float xr[8*DM];
  __shared__ int sflag;
  int tid = threadIdx.x; // 384
  detect_bf16((const unsigned short*)xraw, tid, &sflag);
  __syncthreads();
  int l0 = blockIdx.x * 8;
  if (sflag){
    const __hip_bfloat16* xb = (const __hip_bfloat16*)xraw + (size_t)l0*DM;
    for (int i = tid; i < 8*DM; i += 384) xr[i] = b2f(xb[i]);
  } else {
    const float* xf = (const float*)xraw + (size_t)l0*DM;
    for (int i = tid; i < 8*DM; i += 384) xr[i] = xf[i];
  }
  __syncthreads();
  int e = tid;
  float acc[8];
  #pragma unroll
  for (int i=0;i<8;i++) acc[i]=0.f;
  const float4* wr4 = (const float4*)(w + (size_t)e*DM);   // row is 96 floats, 16B-aligned
  #pragma unroll 4
  for (int c4=0;c4<DM/4;c4++){
    float4 wv = wr4[c4];
    int c = c4*4;
    #pragma unroll
    for (int i=0;i<8;i++){
      float a = acc[i];
      a = fmaf(wv.x, xr[i*DM+c  ], a);
      a = fmaf(wv.y, xr[i*DM+c+1], a);
      a = fmaf(wv.z, xr[i*DM+c+2], a);
      a = fmaf(wv.w, xr[i*DM+c+3], a);
      acc[i] = a;
    }
  }
  if (e < DI) {
    #pragma unroll
    for (int i=0;i<8;i++) xx[(l0+i)*DI + e] = acc[i];
  } else {
    int e2 = e - DI;
    #pragma unroll
    for (int i=0;i<8;i++) z[(l0+i)*DI + e2] = acc[i];
  }
}

// -------- K2: depthwise 3x3 conv + bias + SiLU; writes xc AND transposed xct --------
__global__ void k_conv(const float* __restrict__ xx,
                       const float* __restrict__ cw,
                       const float* __restrict__ cb,
                       float* __restrict__ xc,
                       float* __restrict__ xct) {
  int l = blockIdx.x;
  int d = threadIdx.x; // 192
  int h = l >> 6, w = l & 63;
  float acc = cb[d];
  #pragma unroll
  for (int ki=0; ki<3; ki++){
    int hh = h + ki - 1;
    if ((unsigned)hh >= 64u) continue;
    #pragma unroll
    for (int kj=0;kj<3;kj++){
      int wj = w + kj - 1;
      if ((unsigned)wj >= 64u) continue;
      acc = fmaf(cw[d*9 + ki*3 + kj], xx[(hh*64+wj)*DI + d], acc);
    }
  }
  float v = acc / (1.f + __expf(-acc));
  xc[l*DI + d] = v;
  xct[(((w<<6)|h))*DI + d] = v;
}

__device__ __forceinline__ int dir_map(int k, int t){
  if (k==0) return t;
  if (k==1) return ((t&63)<<6) | (t>>6);
  if (k==2) return 4095 - t;
  int u = 4095 - t; return ((u&63)<<6) | (u>>6);
}

// -------- K3: x_dbl projection as register-tiled LDS GEMM --------
__global__ void __launch_bounds__(256) k_proj(const float* __restrict__ xc,
                       const float* __restrict__ xpw,
                       float* __restrict__ dts,
                       float* __restrict__ Bb, float* __restrict__ Cb) {
  __shared__ float wl[CPROJ*WS];   // 29.8 KB
  __shared__ float xs[PT*WS];      // 25.1 KB
  int b = blockIdx.x;              // KD * 128
  int k = b >> 7;
  int t_base = (b & 127) * PT;
  int tid = threadIdx.x;
  for (int idx = tid; idx < CPROJ*DI; idx += 256){
    int cc = idx / DI, j = idx - cc*DI;
    wl[cc*WS + j] = xpw[(k*CPROJ + cc)*DI + j];
  }
  for (int idx = tid; idx < PT*DI; idx += 256){
    int tt = idx / DI, j = idx - tt*DI;
    xs[tt*WS + j] = xc[dir_map(k, t_base + tt)*DI + j];
  }
  __syncthreads();
  int tg = tid & 7;        // t-group: cols {tg, tg+8, tg+16, tg+24}
  int ty = tid >> 3;       // 0..31: rows {ty, ty+32 if <38}
  int cc0 = ty;
  int has2 = (ty + 32 < CPROJ);
  int cc1 = has2 ? (ty + 32) : ty;
  float a0x=0.f,a0y=0.f,a0z=0.f,a0w=0.f;
  float a1x=0.f,a1y=0.f,a1z=0.f,a1w=0.f;
  const float4* w0p = (const float4*)&wl[cc0*WS];
  const float4* w1p = (const float4*)&wl[cc1*WS];
  const float4* x0p = (const float4*)&xs[(tg     )*WS];
  const float4* x1p = (const float4*)&xs[(tg +  8)*WS];
  const float4* x2p = (const float4*)&xs[(tg + 16)*WS];
  const float4* x3p = (const float4*)&xs[(tg + 24)*WS];
  #pragma unroll 4
  for (int jc = 0; jc < DI/4; jc++){
    float4 w0 = w0p[jc], w1 = w1p[jc];
    float4 x0 = x0p[jc], x1 = x1p[jc], x2 = x2p[jc], x3 = x3p[jc];
    a0x = fmaf(w0.x,x0.x,fmaf(w0.y,x0.y,fmaf(w0.z,x0.z,fmaf(w0.w,x0.w,a0x))));
    a0y = fmaf(w0.x,x1.x,fmaf(w0.y,x1.y,fmaf(w0.z,x1.z,fmaf(w0.w,x1.w,a0y))));
    a0z = fmaf(w0.x,x2.x,fmaf(w0.y,x2.y,fmaf(w0.z,x2.z,fmaf(w0.w,x2.w,a0z))));
    a0w = fmaf(w0.x,x3.x,fmaf(w0.y,x3.y,fmaf(w0.z,x3.z,fmaf(w0.w,x3.w,a0w))));
    a1x = fmaf(w1.x,x0.x,fmaf(w1.y,x0.y,fmaf(w1.z,x0.z,fmaf(w1.w,x0.w,a1x))));
    a1y = fmaf(w1.x,x1.x,fmaf(w1.y,x1.y,fmaf(w1.z,x1.z,fmaf(w1.w,x1.w,a1y))));
    a1z = fmaf(w1.x,x2.x,fmaf(w1.y,x2.y,fmaf(w1.z,x2.z,fmaf(w1.w,x2.w,a1z))));
    a1w = fmaf(w1.x,x3.x,fmaf(w1.y,x3.y,fmaf(w1.z,x3.z,fmaf(w1.w,x3.w,a1w))));
  }
  float accs0[4] = {a0x,a0y,a0z,a0w};
  float accs1[4] = {a1x,a1y,a1z,a1w};
  #pragma unroll
  for (int i=0;i<4;i++){
    int t = t_base + tg + 8*i;
    size_t kt = (size_t)k*LL + t;
    {
      int cc = cc0; float v = accs0[i];
      if (cc < RK)            dts[kt*RKP + cc] = v;
      else if (cc < RK+NS)    Bb [kt*NS + (cc-RK)] = v;
      else                    Cb [kt*NS + (cc-RK-NS)] = v;
    }
    if (has2){
      int cc = ty + 32; float v = accs1[i];
      if (cc < RK+NS)         Bb [kt*NS + (cc-RK)] = v;
      else                    Cb [kt*NS + (cc-RK-NS)] = v;
    }
  }
}

// -------- K4a: single scan pass; plain y stores; PH interleaved (P,H) --------
template<int CHB>
__global__ void __launch_bounds__(256) k_scan1(
                      const float* __restrict__ xc_hw,
                      const float* __restrict__ xc_wh,
                      const float* __restrict__ dts,
                      const float* __restrict__ Bbuf,
                      const float* __restrict__ Cbuf,
                      const float* __restrict__ A_logs,
                      const float* __restrict__ dtw,
                      const float* __restrict__ dtb,
                      float* __restrict__ PH,
                      float* __restrict__ ydir) {
  constexpr int CS = LL >> CHB;
  int b = blockIdx.x;             // ((k*3+dg3)<<CHB) | c
  int c = b & ((1<<CHB)-1);
  int kg = b >> CHB;
  int k = kg / 3, dg3 = kg - k*3;
  int tid = threadIdx.x;
  int dl = tid >> 2, nq = tid & 3;
  int d = dg3*64 + dl;
  int kd = k*DI + d;
  float4 Al = *(const float4*)&A_logs[kd*NS + nq*4];
  float A0 = -__expf(Al.x)*L2E, A1 = -__expf(Al.y)*L2E;
  float A2 = -__expf(Al.z)*L2E, A3 = -__expf(Al.w)*L2E;
  float bt = dtb[kd];
  float w0 = dtw[kd*RK+0], w1 = dtw[kd*RK+1], w2 = dtw[kd*RK+2];
  float w3 = dtw[kd*RK+3], w4 = dtw[kd*RK+4], w5 = dtw[kd*RK+5];
  const float* dr = dts + ((size_t)k*LL + c*CS)*RKP;
  const float4* bp = (const float4*)(Bbuf + ((size_t)k*LL + c*CS)*NS) + nq;
  const float4* cp = (const float4*)(Cbuf + ((size_t)k*LL + c*CS)*NS) + nq;
  const float* xbase = (k & 1) ? xc_wh : xc_hw;
  int l0 = (k < 2) ? (c*CS) : (4095 - c*CS);
  int lstep = (k < 2) ? DI : -DI;
  const float* xp = xbase + (size_t)l0*DI + d;
  float* yp = ydir + ((size_t)k*LL + c*CS)*DI + d;
  float h0=0.f,h1=0.f,h2=0.f,h3=0.f, cumD=0.f;
  #pragma unroll
  for (int s=0; s<CS; s++){
    float4 lo = *(const float4*)(dr + s*RKP);
    float4 hi = *(const float4*)(dr + s*RKP + 4);
    float v = bt;
    v = fmaf(w0, lo.x, v); v = fmaf(w1, lo.y, v); v = fmaf(w2, lo.z, v);
    v = fmaf(w3, lo.w, v); v = fmaf(w4, hi.x, v); v = fmaf(w5, hi.y, v);
    float sp = (v > 20.f) ? v : __logf(1.f + __expf(v));
    cumD += sp;
    float sx = sp * xp[(ptrdiff_t)s*lstep];
    float4 bv = bp[s*4];
    float4 cv = cp[s*4];
    float a;
    a = exp2f(sp*A0); h0 = fmaf(a, h0, sx*bv.x);
    a = exp2f(sp*A1); h1 = fmaf(a, h1, sx*bv.y);
    a = exp2f(sp*A2); h2 = fmaf(a, h2, sx*bv.z);
    a = exp2f(sp*A3); h3 = fmaf(a, h3, sx*bv.w);
    float y = h0*cv.x + h1*cv.y + h2*cv.z + h3*cv.w;
    y += __shfl_xor(y, 1, 64);
    y += __shfl_xor(y, 2, 64);
    if (nq == 0) yp[s*DI] = y;     // plain store: unique writer per (k,t,d)
  }
  size_t base2 = ((size_t)c*NC + (size_t)kd*NS + nq*4)*2;
  *(float4*)&PH[base2]   = make_float4(exp2f(A0*cumD), h0, exp2f(A1*cumD), h1);
  *(float4*)&PH[base2+4] = make_float4(exp2f(A2*cumD), h2, exp2f(A3*cumD), h3);
}

// -------- K4b: phase-2 combine over interleaved PH; entry state written into .y --------
template<int CHB>
__global__ void __launch_bounds__(256) k_scan2(float2* __restrict__ PH) {
  constexpr int CH = 1 << CHB;
  int idx = blockIdx.x*256 + threadIdx.x;   // < 12288
  float h = 0.f;
  #pragma unroll 8
  for (int c=0;c<CH;c++){
    float2 ph = PH[(size_t)c*NC + idx];
    PH[(size_t)c*NC + idx].y = h;           // overwrite H with entry state
    h = fmaf(ph.x, h, ph.y);
  }
}

// -------- K4c: parallel correction; recomputes SD from dts (bit-identical to scan1) --------
template<int CHB>
__global__ void __launch_bounds__(192) k_corr(
                      const float* __restrict__ Cbuf,
                      const float* __restrict__ dts,
                      const float* __restrict__ A_logs,
                      const float* __restrict__ dtw,
                      const float* __restrict__ dtb,
                      const float2* __restrict__ PH,    // .y = entry states
                      float* __restrict__ ydir) {
  constexpr int CS = LL >> CHB;
  int b = blockIdx.x;              // KD << CHB
  int k = b >> CHB;
  int c = b & ((1<<CHB)-1);
  if (c == 0) return;              // entry state is zero -> no correction
  int t0 = c*CS;
  int d = threadIdx.x;             // 192
  int kd = k*DI + d;
  __shared__ float cs[CS*NS];
  for (int i = d; i < CS*NS; i += 192)
    cs[i] = Cbuf[((size_t)k*LL + t0)*NS + i];
  float bt = dtb[kd];
  float w0 = dtw[kd*RK+0], w1 = dtw[kd*RK+1], w2 = dtw[kd*RK+2];
  float w3 = dtw[kd*RK+3], w4 = dtw[kd*RK+4], w5 = dtw[kd*RK+5];
  float A2[16], he[16];
  {
    const float4* ap = (const float4*)&A_logs[kd*NS];
    const float2* hp = PH + (size_t)c*NC + (size_t)kd*NS;
    #pragma unroll
    for (int i=0;i<4;i++){
      float4 av = ap[i];
      A2[4*i+0] = -__expf(av.x)*L2E; A2[4*i+1] = -__expf(av.y)*L2E;
      A2[4*i+2] = -__expf(av.z)*L2E; A2[4*i+3] = -__expf(av.w)*L2E;
    }
    #pragma unroll
    for (int n=0;n<16;n++) he[n] = hp[n].y;
  }
  __syncthreads();
  const float* dr = dts + ((size_t)k*LL + t0)*RKP;
  float* yp = ydir + ((size_t)k*LL + t0)*DI + d;
  float cumD = 0.f;
  #pragma unroll 4
  for (int s=0; s<CS; s++){
    float4 lo = *(const float4*)(dr + s*RKP);
    float4 hi = *(const float4*)(dr + s*RKP + 4);
    float v = bt;
    v = fmaf(w0, lo.x, v); v = fmaf(w1, lo.y, v); v = fmaf(w2, lo.z, v);
    v = fmaf(w3, lo.w, v); v = fmaf(w4, hi.x, v); v = fmaf(w5, hi.y, v);
    float sp = (v > 20.f) ? v : __logf(1.f + __expf(v));
    cumD += sp;                    // same fma order as scan1 -> bit-identical
    float corr = 0.f;
    #pragma unroll
    for (int n=0;n<16;n++)
      corr = fmaf(cs[s*NS+n]*exp2f(A2[n]*cumD), he[n], corr);
    yp[s*DI] += corr;        // unique owner: scan1 done, one block per chunk
  }
}

// -------- K5: fused gather + LayerNorm + gate + out_proj, 16-l tile --------
__global__ void __launch_bounds__(192) k_out(
                      const float* __restrict__ ydir,
                      const float* __restrict__ xc,
                      const float* __restrict__ z,
                      const float* __restrict__ Ds,
                      const float* __restrict__ ln_g,
                      const float* __restrict__ ln_b,
                      const float* __restrict__ opw,
                      void* __restrict__ out,
                      const unsigned short* __restrict__ xh) {
  __shared__ float gs[OT*WS];      // 12.5 KB: y -> g
  __shared__ float ps[2][OT][12];
  __shared__ float mv[2][OT];
  __shared__ int sflag;
  int tid = threadIdx.x;           // 192
  int d = tid;
  detect_bf16(xh, tid, &sflag);
  int l0 = blockIdx.x * OT;        // 256 blocks
  float dsum = Ds[d] + Ds[DI+d] + Ds[2*DI+d] + Ds[3*DI+d];
  // phase A: y for 16 rows at this d
  #pragma unroll 4
  for (int r=0;r<OT;r++){
    int l = l0 + r;
    int lt = ((l & 63) << 6) | (l >> 6);
    float y = ydir[(size_t)l*DI + d]
            + ydir[((size_t)LL   + lt)*DI + d]
            + ydir[((size_t)2*LL + (4095 - l))*DI + d]
            + ydir[((size_t)3*LL + (4095 - lt))*DI + d];
    gs[r*WS + d] = fmaf(xc[(size_t)l*DI + d], dsum, y);
  }
  __syncthreads();
  // phase B: per-row mean/var; 16 groups x 12 threads
  {
    int r = tid / 12, lane = tid - r*12;
    float s1 = 0.f, s2 = 0.f;
    for (int j = lane; j < DI; j += 12){
      float v = gs[r*WS + j];
      s1 += v; s2 += v*v;
    }
    ps[0][r][lane] = s1; ps[1][r][lane] = s2;
  }
  __syncthreads();
  if (tid < OT){
    float a = 0.f, bb = 0.f;
    #pragma unroll
    for (int j=0;j<12;j++){ a += ps[0][tid][j]; bb += ps[1][tid][j]; }
    float mu = a * (1.f/192.f);
    float var = bb * (1.f/192.f) - mu*mu;
    mv[0][tid] = mu; mv[1][tid] = rsqrtf(var + 1e-5f);
  }
  __syncthreads();
  // phase C: normalize + gate
  float lg = ln_g[d], lb = ln_b[d];
  #pragma unroll 4
  for (int r=0;r<OT;r++){
    float yn = (gs[r*WS + d] - mv[0][r]) * mv[1][r] * lg + lb;
    float zv = z[(size_t)(l0+r)*DI + d];
    gs[r*WS + d] = yn * (zv / (1.f + __expf(-zv)));
  }
  __syncthreads();
  // phase D: out_proj
  int half = tid / 96;             // rows half*8..half*8+7
  int e = tid - half*96;
  int r0 = half*8;
  float acc[8];
  #pragma unroll
  for (int i=0;i<8;i++) acc[i] = 0.f;
  const float4* wrow = (const float4*)(opw + e*DI);
  #pragma unroll 4
  for (int jc = 0; jc < DI/4; jc++){
    float4 w = wrow[jc];
    #pragma unroll
    for (int i=0;i<8;i++){
      float4 gv = *(const float4*)&gs[(r0+i)*WS + jc*4];
      acc[i] = fmaf(w.x,gv.x,fmaf(w.y,gv.y,fmaf(w.z,gv.z,fmaf(w.w,gv.w,acc[i]))));
    }
  }
  int f = sflag;
  #pragma unroll
  for (int i=0;i<8;i++){
    int l = l0 + r0 + i;
    if (f) ((__hip_bfloat16*)out)[l*DM + e] = __float2bfloat16(acc[i]);
    else   ((float*)out)[l*DM + e] = acc[i];
  }
}

extern "C" void kernel_launch(void* const* d_in, const int* in_sizes, int n_in,
                              void* d_out, int out_size, void* d_ws, size_t ws_size,
                              hipStream_t stream) {
  float* ws = (float*)d_ws;
  float* cvt = ws + 16;
  const int off[12] = {0,36864,38592,38784,67968,72576,73344,85632,86400,86592,86784,105216};
  float* c[12];
  c[0] = nullptr;                            // x stays raw
  for (int i = 1; i < 12; i++) c[i] = cvt + off[i-1];

  float* big    = cvt + 105216;
  float* xx     = big;                       // 786432
  float* z      = xx + (size_t)LL*DI;        // 786432
  float* xc     = z  + (size_t)LL*DI;        // 786432
  float* xct    = xc + (size_t)LL*DI;        // 786432
  float* dts    = xct + (size_t)LL*DI;       // 131072 (RKP=8 padded)
  float* Bb     = dts + (size_t)KD*LL*RKP;   // 262144
  float* Cb     = Bb + (size_t)KD*LL*NS;     // 262144
  float* PH     = Cb + (size_t)KD*LL*NS;     // 2*CHn*NC
  // footprint(CHB=7): ~39 MB; (CHB=6): ~33 MB. ws_size measured 256 MiB.
  size_t need128 = (size_t)(16 + 105216 + 4*786432 + 131072 + 2*262144
                            + 2*128*NC + (size_t)KD*LL*DI) * 4;
  int chBits = (ws_size >= need128) ? 7 : 6;
  int CHn = 1 << chBits;
  float* ydir = PH + 2*(size_t)CHn*NC;       // KD*LL*DI = 3145728

  P12 ptrs;
  for (int i = 0; i < 12; i++) ptrs.p[i] = d_in[i];
  k_convert_all<<<(105216 + 255)/256, 256, 0, stream>>>(ptrs, cvt);

  k_inproj<<<LL/8, 384, 0, stream>>>(d_in[0], c[1], xx, z);
  k_conv<<<LL, DI, 0, stream>>>(xx, c[2], c[3], xc, xct);
  k_proj<<<KD*(LL/PT), 256, 0, stream>>>(xc, c[4], dts, Bb, Cb);
  if (chBits == 7){
    k_scan1<7><<<KD*3*128, 256, 0, stream>>>(xc, xct, dts, Bb, Cb, c[7], c[5], c[6],
                                             PH, ydir);
    k_scan2<7><<<NC/256, 256, 0, stream>>>((float2*)PH);
    k_corr<7><<<KD*128, 192, 0, stream>>>(Cb, dts, c[7], c[5], c[6],
                                          (const float2*)PH, ydir);
  } else {
    k_scan1<6><<<KD*3*64, 256, 0, stream>>>(xc, xct, dts, Bb, Cb, c[7], c[5], c[6],
                                            PH, ydir);
    k_scan2<6><<<NC/256, 256, 0, stream>>>((float2*)PH);
    k_corr<6><<<KD*64, 192, 0, stream>>>(Cb, dts, c[7], c[5], c[6],
                                         (const float2*)PH, ydir);
  }
  k_out<<<LL/OT, 192, 0, stream>>>(ydir, xc, z, c[8], c[9], c[10], c[11], d_out,
                                   (const unsigned short*)d_in[0]);
}